// Round 2
// baseline (368.737 us; speedup 1.0000x reference)
//
#include <hip/hip_runtime.h>

typedef __bf16 bf16x8 __attribute__((ext_vector_type(8)));
typedef float f32x4 __attribute__((ext_vector_type(4)));

#define GAS __attribute__((address_space(1)))
#define LAS __attribute__((address_space(3)))

__device__ __forceinline__ unsigned short f32_to_bf16(float f) {
    unsigned int u = __float_as_uint(f);
    u += 0x7FFFu + ((u >> 16) & 1u);   // round-to-nearest-even
    return (unsigned short)(u >> 16);
}

__device__ __forceinline__ void load16(const unsigned short* g, unsigned short* l) {
    // async global->LDS, 16B per lane; LDS dest is wave-uniform base + lane*16
    __builtin_amdgcn_global_load_lds((GAS unsigned int*)g, (LAS unsigned int*)l, 16, 0, 0);
}

// ---------------------------------------------------------------------------
// fp32 -> bf16 elementwise convert (x)
// ---------------------------------------------------------------------------
__global__ __launch_bounds__(256) void convert_f32_bf16(
    const float* __restrict__ in, unsigned short* __restrict__ out, int n4)
{
    int i = blockIdx.x * 256 + threadIdx.x;
    if (i < n4) {
        float4 v = ((const float4*)in)[i];
        ushort4 o;
        o.x = f32_to_bf16(v.x); o.y = f32_to_bf16(v.y);
        o.z = f32_to_bf16(v.z); o.w = f32_to_bf16(v.w);
        ((ushort4*)out)[i] = o;
    }
}

// ---------------------------------------------------------------------------
// 768x768 fp32 -> bf16 transpose (three weights via blockIdx.z)
// ---------------------------------------------------------------------------
__global__ __launch_bounds__(1024) void transpose_w(
    const float* __restrict__ W0, const float* __restrict__ W1, const float* __restrict__ W2,
    unsigned short* __restrict__ T0, unsigned short* __restrict__ T1, unsigned short* __restrict__ T2)
{
    __shared__ float tile[32][33];
    const float* W = (blockIdx.z == 0) ? W0 : (blockIdx.z == 1) ? W1 : W2;
    unsigned short* T = (blockIdx.z == 0) ? T0 : (blockIdx.z == 1) ? T1 : T2;
    int r0 = blockIdx.y * 32, c0 = blockIdx.x * 32;
    tile[threadIdx.y][threadIdx.x] = W[(size_t)(r0 + threadIdx.y) * 768 + c0 + threadIdx.x];
    __syncthreads();
    T[(size_t)(c0 + threadIdx.y) * 768 + r0 + threadIdx.x] = f32_to_bf16(tile[threadIdx.x][threadIdx.y]);
}

// ---------------------------------------------------------------------------
// NT GEMM (m97 structure): C[M,N] = alpha * A[M,K] . B[N,K]^T
// A,B bf16 row-major; C bf16 or fp32. 128x128 tile, BK=64, 256 threads.
// All M,N multiples of 128, K multiple of 64 (guaranteed by caller).
// ---------------------------------------------------------------------------
template <typename CT>
__global__ __launch_bounds__(256) void gemm_nt(
    const unsigned short* __restrict__ A, const unsigned short* __restrict__ B,
    CT* __restrict__ C, int K, int lda, int ldb, int ldc,
    size_t sA, size_t sB, size_t sC, float alpha)
{
    A += (size_t)blockIdx.z * sA;
    B += (size_t)blockIdx.z * sB;
    C += (size_t)blockIdx.z * sC;
    const int m0 = blockIdx.y * 128;
    const int n0 = blockIdx.x * 128;
    const int t = threadIdx.x;
    const int lane = t & 63;
    const int w = t >> 6;
    const int wm = (w >> 1) * 64;   // wave row offset in tile
    const int wn = (w & 1) * 64;    // wave col offset in tile

    __shared__ unsigned short At[128 * 64];
    __shared__ unsigned short Bt[128 * 64];

    f32x4 acc[4][4];
#pragma unroll
    for (int i = 0; i < 4; ++i)
#pragma unroll
        for (int j = 0; j < 4; ++j) acc[i][j] = (f32x4){0.f, 0.f, 0.f, 0.f};

    const int r15 = lane & 15;
    const int q8 = (lane >> 4) * 8;

    for (int k0 = 0; k0 < K; k0 += 64) {
        // stage A[128][64], B[128][64] via async 16B global->LDS
#pragma unroll
        for (int i = 0; i < 4; ++i) {
            const int c = i * 256 + t;       // chunk id, 8 chunks (of 8 bf16) per row
            const int row = c >> 3;
            const int cc = (c & 7) * 8;
            load16(A + (size_t)(m0 + row) * lda + k0 + cc, &At[c * 8]);
            load16(B + (size_t)(n0 + row) * ldb + k0 + cc, &Bt[c * 8]);
        }
        __syncthreads();   // compiler emits vmcnt(0) drain before barrier

#pragma unroll
        for (int ks = 0; ks < 2; ++ks) {
            bf16x8 af[4], bf[4];
#pragma unroll
            for (int mi = 0; mi < 4; ++mi)
                af[mi] = *(const bf16x8*)&At[(wm + mi * 16 + r15) * 64 + ks * 32 + q8];
#pragma unroll
            for (int ni = 0; ni < 4; ++ni)
                bf[ni] = *(const bf16x8*)&Bt[(wn + ni * 16 + r15) * 64 + ks * 32 + q8];
#pragma unroll
            for (int mi = 0; mi < 4; ++mi)
#pragma unroll
                for (int ni = 0; ni < 4; ++ni)
                    acc[mi][ni] = __builtin_amdgcn_mfma_f32_16x16x32_bf16(
                        af[mi], bf[ni], acc[mi][ni], 0, 0, 0);
        }
        __syncthreads();
    }

    // epilogue: C/D layout col=lane&15, row=(lane>>4)*4+reg  [m89/m91 verified]
    const int cr = (lane >> 4) * 4;
#pragma unroll
    for (int mi = 0; mi < 4; ++mi) {
#pragma unroll
        for (int ni = 0; ni < 4; ++ni) {
            const int gm = m0 + wm + mi * 16 + cr;
            const int gn = n0 + wn + ni * 16 + r15;
#pragma unroll
            for (int r = 0; r < 4; ++r) {
                float v = alpha * acc[mi][ni][r];
                if constexpr (sizeof(CT) == 2)
                    C[(size_t)(gm + r) * ldc + gn] = (CT)f32_to_bf16(v);
                else
                    C[(size_t)(gm + r) * ldc + gn] = v;
            }
        }
    }
}

// ---------------------------------------------------------------------------
// Split-K O-GEMM: Part[z] = P[batch] tile . Vt[batch] tile over K-chunk.
// z = split*2 + batch, split in [0,4), batch in [0,2). K-chunk = 1024.
// A = P [batch][4096][4096] bf16, B = Vt [768][8192] bf16 (batch = col half),
// C = Part [z][4096][768] fp32.
// ---------------------------------------------------------------------------
__global__ __launch_bounds__(256) void gemm_nt_splitk(
    const unsigned short* __restrict__ P, const unsigned short* __restrict__ Vt,
    float* __restrict__ Part)
{
    const int z = blockIdx.z;
    const int batch = z & 1;
    const int split = z >> 1;
    const unsigned short* A = P + (size_t)batch * 16777216 + (size_t)split * 1024;
    const unsigned short* B = Vt + (size_t)batch * 4096 + (size_t)split * 1024;
    float* C = Part + (size_t)z * 3145728;
    const int lda = 4096, ldb = 8192, ldc = 768;
    const int m0 = blockIdx.y * 128;
    const int n0 = blockIdx.x * 128;
    const int t = threadIdx.x;
    const int lane = t & 63;
    const int w = t >> 6;
    const int wm = (w >> 1) * 64;
    const int wn = (w & 1) * 64;

    __shared__ unsigned short At[128 * 64];
    __shared__ unsigned short Bt[128 * 64];

    f32x4 acc[4][4];
#pragma unroll
    for (int i = 0; i < 4; ++i)
#pragma unroll
        for (int j = 0; j < 4; ++j) acc[i][j] = (f32x4){0.f, 0.f, 0.f, 0.f};

    const int r15 = lane & 15;
    const int q8 = (lane >> 4) * 8;

    for (int k0 = 0; k0 < 1024; k0 += 64) {
#pragma unroll
        for (int i = 0; i < 4; ++i) {
            const int c = i * 256 + t;
            const int row = c >> 3;
            const int cc = (c & 7) * 8;
            load16(A + (size_t)(m0 + row) * lda + k0 + cc, &At[c * 8]);
            load16(B + (size_t)(n0 + row) * ldb + k0 + cc, &Bt[c * 8]);
        }
        __syncthreads();

#pragma unroll
        for (int ks = 0; ks < 2; ++ks) {
            bf16x8 af[4], bf[4];
#pragma unroll
            for (int mi = 0; mi < 4; ++mi)
                af[mi] = *(const bf16x8*)&At[(wm + mi * 16 + r15) * 64 + ks * 32 + q8];
#pragma unroll
            for (int ni = 0; ni < 4; ++ni)
                bf[ni] = *(const bf16x8*)&Bt[(wn + ni * 16 + r15) * 64 + ks * 32 + q8];
#pragma unroll
            for (int mi = 0; mi < 4; ++mi)
#pragma unroll
                for (int ni = 0; ni < 4; ++ni)
                    acc[mi][ni] = __builtin_amdgcn_mfma_f32_16x16x32_bf16(
                        af[mi], bf[ni], acc[mi][ni], 0, 0, 0);
        }
        __syncthreads();
    }

    const int cr = (lane >> 4) * 4;
#pragma unroll
    for (int mi = 0; mi < 4; ++mi) {
#pragma unroll
        for (int ni = 0; ni < 4; ++ni) {
            const int gm = m0 + wm + mi * 16 + cr;
            const int gn = n0 + wn + ni * 16 + r15;
#pragma unroll
            for (int r = 0; r < 4; ++r)
                C[(size_t)(gm + r) * ldc + gn] = acc[mi][ni][r];
        }
    }
}

// ---------------------------------------------------------------------------
// Reduce 4 split-K partials: out[i] = sum_s Part[s*6291456 + i], float4-wide.
// ---------------------------------------------------------------------------
__global__ __launch_bounds__(256) void reduce4(
    const float* __restrict__ Part, float* __restrict__ out)
{
    const size_t i = (size_t)blockIdx.x * 256 + threadIdx.x;  // float4 index
    const f32x4* p = (const f32x4*)Part;
    f32x4 v = p[i] + p[i + 1572864] + p[i + 2 * 1572864] + p[i + 3 * 1572864];
    ((f32x4*)out)[i] = v;
}

// ---------------------------------------------------------------------------
// Row softmax: S (fp32, 4096 cols) -> P (bf16). One block per row.
// ---------------------------------------------------------------------------
__global__ __launch_bounds__(256) void softmax_rows(
    const float* __restrict__ S, unsigned short* __restrict__ P)
{
    const size_t row = blockIdx.x;
    const float* s = S + row * 4096;
    unsigned short* p = P + row * 4096;
    const int t = threadIdx.x;
    const int wv = t >> 6, ln = t & 63;

    float4 v[4];
    float lmax = -1e30f;
#pragma unroll
    for (int i = 0; i < 4; ++i) {
        v[i] = ((const float4*)s)[t + i * 256];
        lmax = fmaxf(lmax, fmaxf(fmaxf(v[i].x, v[i].y), fmaxf(v[i].z, v[i].w)));
    }
#pragma unroll
    for (int off = 32; off > 0; off >>= 1) lmax = fmaxf(lmax, __shfl_down(lmax, off, 64));
    __shared__ float redm[4], reds[4];
    if (ln == 0) redm[wv] = lmax;
    __syncthreads();
    const float rmax = fmaxf(fmaxf(redm[0], redm[1]), fmaxf(redm[2], redm[3]));

    float lsum = 0.f;
#pragma unroll
    for (int i = 0; i < 4; ++i) {
        v[i].x = __expf(v[i].x - rmax);
        v[i].y = __expf(v[i].y - rmax);
        v[i].z = __expf(v[i].z - rmax);
        v[i].w = __expf(v[i].w - rmax);
        lsum += v[i].x + v[i].y + v[i].z + v[i].w;
    }
#pragma unroll
    for (int off = 32; off > 0; off >>= 1) lsum += __shfl_down(lsum, off, 64);
    if (ln == 0) reds[wv] = lsum;
    __syncthreads();
    const float inv = 1.f / (reds[0] + reds[1] + reds[2] + reds[3]);

#pragma unroll
    for (int i = 0; i < 4; ++i) {
        ushort4 o;
        o.x = f32_to_bf16(v[i].x * inv);
        o.y = f32_to_bf16(v[i].y * inv);
        o.z = f32_to_bf16(v[i].z * inv);
        o.w = f32_to_bf16(v[i].w * inv);
        ((ushort4*)p)[t + i * 256] = o;
    }
}

// ---------------------------------------------------------------------------
extern "C" void kernel_launch(void* const* d_in, const int* in_sizes, int n_in,
                              void* d_out, int out_size, void* d_ws, size_t ws_size,
                              hipStream_t stream) {
    const float* x  = (const float*)d_in[0];   // [2,4096,768]
    const float* Wq = (const float*)d_in[1];   // [768,768]
    const float* Wk = (const float*)d_in[2];
    const float* Wv = (const float*)d_in[3];
    float* out = (float*)d_out;                // [2,4096,768] fp32

    char* base = (char*)d_ws;
    size_t off = 0;
    auto alloc = [&](size_t b) { char* p = base + off; off += (b + 255) & ~(size_t)255; return p; };

    unsigned short* Xbf = (unsigned short*)alloc(8192ull * 768 * 2);   // x as bf16
    unsigned short* WqT = (unsigned short*)alloc(768ull * 768 * 2);    // Wq^T bf16
    unsigned short* WkT = (unsigned short*)alloc(768ull * 768 * 2);    // contiguous after WqT
    unsigned short* WvT = (unsigned short*)alloc(768ull * 768 * 2);
    unsigned short* Qb  = (unsigned short*)alloc(8192ull * 768 * 2);   // Q bf16 [8192,768]
    unsigned short* Kb  = (unsigned short*)alloc(8192ull * 768 * 2);   // contiguous after Qb
    unsigned short* Vt  = (unsigned short*)alloc(768ull * 8192 * 2);   // V^T bf16 [768,8192]
    float*          S   = (float*)alloc(2ull * 4096 * 4096 * 4);       // scores fp32; later reused for O partials
    unsigned short* P   = (unsigned short*)alloc(2ull * 4096 * 4096 * 2); // softmax bf16
    (void)ws_size; (void)in_sizes; (void)n_in; (void)out_size;

    // 1) x -> bf16
    convert_f32_bf16<<<dim3(6144), dim3(256), 0, stream>>>(x, Xbf, 8192 * 768 / 4);
    // 2) W -> W^T bf16 (all three)
    transpose_w<<<dim3(24, 24, 3), dim3(32, 32), 0, stream>>>(Wq, Wk, Wv, WqT, WkT, WvT);
    // 3) Q,K = Xbf . W^T^T  (NT; z=0 -> Q, z=1 -> K via buffer strides)
    gemm_nt<unsigned short><<<dim3(6, 64, 2), dim3(256), 0, stream>>>(
        Xbf, WqT, Qb, 768, 768, 768, 768,
        /*sA*/ 0, /*sB*/ 589824, /*sC*/ 6291456, 1.0f);
    // 4) V^T = WvT . Xbf^T  (NT) -> [768, 8192]
    gemm_nt<unsigned short><<<dim3(64, 6, 1), dim3(256), 0, stream>>>(
        WvT, Xbf, Vt, 768, 768, 768, 8192, 0, 0, 0, 1.0f);
    // 5) S = (Q . K^T) / sqrt(768), fp32, per batch
    gemm_nt<float><<<dim3(32, 32, 2), dim3(256), 0, stream>>>(
        Qb, Kb, S, 768, 768, 768, 4096,
        /*sA*/ 3145728ull, /*sB*/ 3145728ull, /*sC*/ 16777216ull, 0.03608439182435161f);
    // 6) row softmax -> P bf16
    softmax_rows<<<dim3(8192), dim3(256), 0, stream>>>(S, P);
    // 7) O = P . V via 4-way split-K into partials (reusing S buffer), then reduce
    gemm_nt_splitk<<<dim3(6, 32, 8), dim3(256), 0, stream>>>(P, Vt, (float*)S);
    reduce4<<<dim3(6144), dim3(256), 0, stream>>>((const float*)S, out);
}

// Round 3
// 367.542 us; speedup vs baseline: 1.0033x; 1.0033x over previous
//
#include <hip/hip_runtime.h>

typedef __bf16 bf16x8 __attribute__((ext_vector_type(8)));
typedef float f32x4 __attribute__((ext_vector_type(4)));

#define GAS __attribute__((address_space(1)))
#define LAS __attribute__((address_space(3)))

__device__ __forceinline__ unsigned short f32_to_bf16(float f) {
    unsigned int u = __float_as_uint(f);
    u += 0x7FFFu + ((u >> 16) & 1u);   // round-to-nearest-even
    return (unsigned short)(u >> 16);
}

__device__ __forceinline__ void load16(const unsigned short* g, unsigned short* l) {
    // async global->LDS, 16B per lane; LDS dest is wave-uniform base + lane*16
    __builtin_amdgcn_global_load_lds((GAS unsigned int*)g, (LAS unsigned int*)l, 16, 0, 0);
}

// ---------------------------------------------------------------------------
// fp32 -> bf16 elementwise convert (x)
// ---------------------------------------------------------------------------
__global__ __launch_bounds__(256) void convert_f32_bf16(
    const float* __restrict__ in, unsigned short* __restrict__ out, int n4)
{
    int i = blockIdx.x * 256 + threadIdx.x;
    if (i < n4) {
        float4 v = ((const float4*)in)[i];
        ushort4 o;
        o.x = f32_to_bf16(v.x); o.y = f32_to_bf16(v.y);
        o.z = f32_to_bf16(v.z); o.w = f32_to_bf16(v.w);
        ((ushort4*)out)[i] = o;
    }
}

// ---------------------------------------------------------------------------
// 768x768 fp32 -> bf16 transpose (three weights via blockIdx.z)
// ---------------------------------------------------------------------------
__global__ __launch_bounds__(1024) void transpose_w(
    const float* __restrict__ W0, const float* __restrict__ W1, const float* __restrict__ W2,
    unsigned short* __restrict__ T0, unsigned short* __restrict__ T1, unsigned short* __restrict__ T2)
{
    __shared__ float tile[32][33];
    const float* W = (blockIdx.z == 0) ? W0 : (blockIdx.z == 1) ? W1 : W2;
    unsigned short* T = (blockIdx.z == 0) ? T0 : (blockIdx.z == 1) ? T1 : T2;
    int r0 = blockIdx.y * 32, c0 = blockIdx.x * 32;
    tile[threadIdx.y][threadIdx.x] = W[(size_t)(r0 + threadIdx.y) * 768 + c0 + threadIdx.x];
    __syncthreads();
    T[(size_t)(c0 + threadIdx.y) * 768 + r0 + threadIdx.x] = f32_to_bf16(tile[threadIdx.x][threadIdx.y]);
}

// ---------------------------------------------------------------------------
// NT GEMM (m97 structure): C[M,N] = alpha * A[M,K] . B[N,K]^T
// A,B bf16 row-major; C bf16 or fp32. 128x128 tile, BK=64, 256 threads.
// ---------------------------------------------------------------------------
template <typename CT>
__global__ __launch_bounds__(256) void gemm_nt(
    const unsigned short* __restrict__ A, const unsigned short* __restrict__ B,
    CT* __restrict__ C, int K, int lda, int ldb, int ldc,
    size_t sA, size_t sB, size_t sC, float alpha)
{
    A += (size_t)blockIdx.z * sA;
    B += (size_t)blockIdx.z * sB;
    C += (size_t)blockIdx.z * sC;
    const int m0 = blockIdx.y * 128;
    const int n0 = blockIdx.x * 128;
    const int t = threadIdx.x;
    const int lane = t & 63;
    const int w = t >> 6;
    const int wm = (w >> 1) * 64;   // wave row offset in tile
    const int wn = (w & 1) * 64;    // wave col offset in tile

    __shared__ unsigned short At[128 * 64];
    __shared__ unsigned short Bt[128 * 64];

    f32x4 acc[4][4];
#pragma unroll
    for (int i = 0; i < 4; ++i)
#pragma unroll
        for (int j = 0; j < 4; ++j) acc[i][j] = (f32x4){0.f, 0.f, 0.f, 0.f};

    const int r15 = lane & 15;
    const int q8 = (lane >> 4) * 8;

    for (int k0 = 0; k0 < K; k0 += 64) {
#pragma unroll
        for (int i = 0; i < 4; ++i) {
            const int c = i * 256 + t;       // chunk id, 8 chunks (of 8 bf16) per row
            const int row = c >> 3;
            const int cc = (c & 7) * 8;
            load16(A + (size_t)(m0 + row) * lda + k0 + cc, &At[c * 8]);
            load16(B + (size_t)(n0 + row) * ldb + k0 + cc, &Bt[c * 8]);
        }
        __syncthreads();

#pragma unroll
        for (int ks = 0; ks < 2; ++ks) {
            bf16x8 af[4], bf[4];
#pragma unroll
            for (int mi = 0; mi < 4; ++mi)
                af[mi] = *(const bf16x8*)&At[(wm + mi * 16 + r15) * 64 + ks * 32 + q8];
#pragma unroll
            for (int ni = 0; ni < 4; ++ni)
                bf[ni] = *(const bf16x8*)&Bt[(wn + ni * 16 + r15) * 64 + ks * 32 + q8];
#pragma unroll
            for (int mi = 0; mi < 4; ++mi)
#pragma unroll
                for (int ni = 0; ni < 4; ++ni)
                    acc[mi][ni] = __builtin_amdgcn_mfma_f32_16x16x32_bf16(
                        af[mi], bf[ni], acc[mi][ni], 0, 0, 0);
        }
        __syncthreads();
    }

    // epilogue: C/D layout col=lane&15, row=(lane>>4)*4+reg  [m89/m91 verified]
    const int cr = (lane >> 4) * 4;
#pragma unroll
    for (int mi = 0; mi < 4; ++mi) {
#pragma unroll
        for (int ni = 0; ni < 4; ++ni) {
            const int gm = m0 + wm + mi * 16 + cr;
            const int gn = n0 + wn + ni * 16 + r15;
#pragma unroll
            for (int r = 0; r < 4; ++r) {
                float v = alpha * acc[mi][ni][r];
                if constexpr (sizeof(CT) == 2)
                    C[(size_t)(gm + r) * ldc + gn] = (CT)f32_to_bf16(v);
                else
                    C[(size_t)(gm + r) * ldc + gn] = v;
            }
        }
    }
}

// ---------------------------------------------------------------------------
// Split-K O-GEMM with XCD-grouped swizzle.
// 1D grid of 768 blocks. Decode so the 6 n-blocks sharing one P-chunk get the
// same (blockIdx % 8) residue -> same XCD -> P fetched once into that L2.
//   u = m*4 + split*2 + batch  (u in [0,256); m in [0,32), split in [0,2))
//   f = (u%8) + 8*(n + 6*(u/8)),  n in [0,6)
// K-chunk = 2048. Part[z= split*2+batch][4096][768] fp32.
// ---------------------------------------------------------------------------
__global__ __launch_bounds__(256) void gemm_nt_splitk(
    const unsigned short* __restrict__ P, const unsigned short* __restrict__ Vt,
    float* __restrict__ Part)
{
    const int f = blockIdx.x;
    const int r8 = f & 7;
    const int tq = f >> 3;            // 0..95
    const int n  = tq % 6;
    const int v  = tq / 6;            // 0..15
    const int u  = v * 8 + r8;        // 0..127
    const int batch = u & 1;
    const int split = (u >> 1) & 1;
    const int m = u >> 2;             // 0..31

    const unsigned short* A = P + (size_t)batch * 16777216 + (size_t)split * 2048;
    const unsigned short* B = Vt + (size_t)batch * 4096 + (size_t)split * 2048;
    float* C = Part + (size_t)(split * 2 + batch) * 3145728;
    const int lda = 4096, ldb = 8192, ldc = 768;
    const int m0 = m * 128;
    const int n0 = n * 128;
    const int t = threadIdx.x;
    const int lane = t & 63;
    const int w = t >> 6;
    const int wm = (w >> 1) * 64;
    const int wn = (w & 1) * 64;

    __shared__ unsigned short At[128 * 64];
    __shared__ unsigned short Bt[128 * 64];

    f32x4 acc[4][4];
#pragma unroll
    for (int i = 0; i < 4; ++i)
#pragma unroll
        for (int j = 0; j < 4; ++j) acc[i][j] = (f32x4){0.f, 0.f, 0.f, 0.f};

    const int r15 = lane & 15;
    const int q8 = (lane >> 4) * 8;

    for (int k0 = 0; k0 < 2048; k0 += 64) {
#pragma unroll
        for (int i = 0; i < 4; ++i) {
            const int c = i * 256 + t;
            const int row = c >> 3;
            const int cc = (c & 7) * 8;
            load16(A + (size_t)(m0 + row) * lda + k0 + cc, &At[c * 8]);
            load16(B + (size_t)(n0 + row) * ldb + k0 + cc, &Bt[c * 8]);
        }
        __syncthreads();

#pragma unroll
        for (int ks = 0; ks < 2; ++ks) {
            bf16x8 af[4], bf[4];
#pragma unroll
            for (int mi = 0; mi < 4; ++mi)
                af[mi] = *(const bf16x8*)&At[(wm + mi * 16 + r15) * 64 + ks * 32 + q8];
#pragma unroll
            for (int ni = 0; ni < 4; ++ni)
                bf[ni] = *(const bf16x8*)&Bt[(wn + ni * 16 + r15) * 64 + ks * 32 + q8];
#pragma unroll
            for (int mi = 0; mi < 4; ++mi)
#pragma unroll
                for (int ni = 0; ni < 4; ++ni)
                    acc[mi][ni] = __builtin_amdgcn_mfma_f32_16x16x32_bf16(
                        af[mi], bf[ni], acc[mi][ni], 0, 0, 0);
        }
        __syncthreads();
    }

    const int cr = (lane >> 4) * 4;
#pragma unroll
    for (int mi = 0; mi < 4; ++mi) {
#pragma unroll
        for (int ni = 0; ni < 4; ++ni) {
            const int gm = m0 + wm + mi * 16 + cr;
            const int gn = n0 + wn + ni * 16 + r15;
#pragma unroll
            for (int r = 0; r < 4; ++r)
                C[(size_t)(gm + r) * ldc + gn] = acc[mi][ni][r];
        }
    }
}

// ---------------------------------------------------------------------------
// Reduce 2 split-K partials: out4[i] = p4[i] + p4[i + 1572864]
// (Part layout z = split*2 + batch; out j: batch = j/3145728 floats)
// ---------------------------------------------------------------------------
__global__ __launch_bounds__(256) void reduce2(
    const float* __restrict__ Part, float* __restrict__ out)
{
    const size_t i = (size_t)blockIdx.x * 256 + threadIdx.x;  // float4 index
    const f32x4* p = (const f32x4*)Part;
    ((f32x4*)out)[i] = p[i] + p[i + 1572864];
}

// ---------------------------------------------------------------------------
// Row softmax: S (fp32, 4096 cols) -> P (bf16). One block per row.
// ---------------------------------------------------------------------------
__global__ __launch_bounds__(256) void softmax_rows(
    const float* __restrict__ S, unsigned short* __restrict__ P)
{
    const size_t row = blockIdx.x;
    const float* s = S + row * 4096;
    unsigned short* p = P + row * 4096;
    const int t = threadIdx.x;
    const int wv = t >> 6, ln = t & 63;

    float4 v[4];
    float lmax = -1e30f;
#pragma unroll
    for (int i = 0; i < 4; ++i) {
        v[i] = ((const float4*)s)[t + i * 256];
        lmax = fmaxf(lmax, fmaxf(fmaxf(v[i].x, v[i].y), fmaxf(v[i].z, v[i].w)));
    }
#pragma unroll
    for (int off = 32; off > 0; off >>= 1) lmax = fmaxf(lmax, __shfl_down(lmax, off, 64));
    __shared__ float redm[4], reds[4];
    if (ln == 0) redm[wv] = lmax;
    __syncthreads();
    const float rmax = fmaxf(fmaxf(redm[0], redm[1]), fmaxf(redm[2], redm[3]));

    float lsum = 0.f;
#pragma unroll
    for (int i = 0; i < 4; ++i) {
        v[i].x = __expf(v[i].x - rmax);
        v[i].y = __expf(v[i].y - rmax);
        v[i].z = __expf(v[i].z - rmax);
        v[i].w = __expf(v[i].w - rmax);
        lsum += v[i].x + v[i].y + v[i].z + v[i].w;
    }
#pragma unroll
    for (int off = 32; off > 0; off >>= 1) lsum += __shfl_down(lsum, off, 64);
    if (ln == 0) reds[wv] = lsum;
    __syncthreads();
    const float inv = 1.f / (reds[0] + reds[1] + reds[2] + reds[3]);

#pragma unroll
    for (int i = 0; i < 4; ++i) {
        ushort4 o;
        o.x = f32_to_bf16(v[i].x * inv);
        o.y = f32_to_bf16(v[i].y * inv);
        o.z = f32_to_bf16(v[i].z * inv);
        o.w = f32_to_bf16(v[i].w * inv);
        ((ushort4*)p)[t + i * 256] = o;
    }
}

// ---------------------------------------------------------------------------
extern "C" void kernel_launch(void* const* d_in, const int* in_sizes, int n_in,
                              void* d_out, int out_size, void* d_ws, size_t ws_size,
                              hipStream_t stream) {
    const float* x  = (const float*)d_in[0];   // [2,4096,768]
    const float* Wq = (const float*)d_in[1];   // [768,768]
    const float* Wk = (const float*)d_in[2];
    const float* Wv = (const float*)d_in[3];
    float* out = (float*)d_out;                // [2,4096,768] fp32

    char* base = (char*)d_ws;
    size_t off = 0;
    auto alloc = [&](size_t b) { char* p = base + off; off += (b + 255) & ~(size_t)255; return p; };

    unsigned short* Xbf = (unsigned short*)alloc(8192ull * 768 * 2);   // x as bf16
    unsigned short* WqT = (unsigned short*)alloc(768ull * 768 * 2);    // Wq^T bf16
    unsigned short* WkT = (unsigned short*)alloc(768ull * 768 * 2);    // contiguous after WqT
    unsigned short* WvT = (unsigned short*)alloc(768ull * 768 * 2);
    unsigned short* Qb  = (unsigned short*)alloc(8192ull * 768 * 2);   // Q bf16 [8192,768]
    unsigned short* Kb  = (unsigned short*)alloc(8192ull * 768 * 2);   // contiguous after Qb
    unsigned short* Vt  = (unsigned short*)alloc(768ull * 8192 * 2);   // V^T bf16 [768,8192]
    float*          S   = (float*)alloc(2ull * 4096 * 4096 * 4);       // scores fp32; reused for O partials
    unsigned short* P   = (unsigned short*)alloc(2ull * 4096 * 4096 * 2); // softmax bf16
    (void)ws_size; (void)in_sizes; (void)n_in; (void)out_size;

    // 1) x -> bf16
    convert_f32_bf16<<<dim3(6144), dim3(256), 0, stream>>>(x, Xbf, 8192 * 768 / 4);
    // 2) W -> W^T bf16 (all three)
    transpose_w<<<dim3(24, 24, 3), dim3(32, 32), 0, stream>>>(Wq, Wk, Wv, WqT, WkT, WvT);
    // 3) Q,K = Xbf . W^T^T  (NT; z=0 -> Q, z=1 -> K via buffer strides)
    gemm_nt<unsigned short><<<dim3(6, 64, 2), dim3(256), 0, stream>>>(
        Xbf, WqT, Qb, 768, 768, 768, 768,
        /*sA*/ 0, /*sB*/ 589824, /*sC*/ 6291456, 1.0f);
    // 4) V^T = WvT . Xbf^T  (NT) -> [768, 8192]
    gemm_nt<unsigned short><<<dim3(64, 6, 1), dim3(256), 0, stream>>>(
        WvT, Xbf, Vt, 768, 768, 768, 8192, 0, 0, 0, 1.0f);
    // 5) S = (Q . K^T) / sqrt(768), fp32, per batch
    gemm_nt<float><<<dim3(32, 32, 2), dim3(256), 0, stream>>>(
        Qb, Kb, S, 768, 768, 768, 4096,
        /*sA*/ 3145728ull, /*sB*/ 3145728ull, /*sC*/ 16777216ull, 0.03608439182435161f);
    // 6) row softmax -> P bf16
    softmax_rows<<<dim3(8192), dim3(256), 0, stream>>>(S, P);
    // 7) O = P . V via 2-way split-K, XCD-grouped swizzle, 768 blocks all-resident
    gemm_nt_splitk<<<dim3(768), dim3(256), 0, stream>>>(P, Vt, (float*)S);
    reduce2<<<dim3(6144), dim3(256), 0, stream>>>((const float*)S, out);
}

// Round 4
// 306.091 us; speedup vs baseline: 1.2047x; 1.2008x over previous
//
#include <hip/hip_runtime.h>

typedef __bf16 bf16x8 __attribute__((ext_vector_type(8)));
typedef float f32x4 __attribute__((ext_vector_type(4)));

#define GAS __attribute__((address_space(1)))
#define LAS __attribute__((address_space(3)))

__device__ __forceinline__ unsigned short f32_to_bf16(float f) {
    unsigned int u = __float_as_uint(f);
    u += 0x7FFFu + ((u >> 16) & 1u);   // round-to-nearest-even
    return (unsigned short)(u >> 16);
}

__device__ __forceinline__ void load16(const unsigned short* g, unsigned short* l) {
    // async global->LDS, 16B per lane; LDS dest is wave-uniform base + lane*16
    __builtin_amdgcn_global_load_lds((GAS unsigned int*)g, (LAS unsigned int*)l, 16, 0, 0);
}

// ---------------------------------------------------------------------------
// fp32 -> bf16 elementwise convert (x)
// ---------------------------------------------------------------------------
__global__ __launch_bounds__(256) void convert_f32_bf16(
    const float* __restrict__ in, unsigned short* __restrict__ out, int n4)
{
    int i = blockIdx.x * 256 + threadIdx.x;
    if (i < n4) {
        float4 v = ((const float4*)in)[i];
        ushort4 o;
        o.x = f32_to_bf16(v.x); o.y = f32_to_bf16(v.y);
        o.z = f32_to_bf16(v.z); o.w = f32_to_bf16(v.w);
        ((ushort4*)out)[i] = o;
    }
}

// ---------------------------------------------------------------------------
// 768x768 fp32 -> bf16 transpose (three weights via blockIdx.z)
// ---------------------------------------------------------------------------
__global__ __launch_bounds__(1024) void transpose_w(
    const float* __restrict__ W0, const float* __restrict__ W1, const float* __restrict__ W2,
    unsigned short* __restrict__ T0, unsigned short* __restrict__ T1, unsigned short* __restrict__ T2)
{
    __shared__ float tile[32][33];
    const float* W = (blockIdx.z == 0) ? W0 : (blockIdx.z == 1) ? W1 : W2;
    unsigned short* T = (blockIdx.z == 0) ? T0 : (blockIdx.z == 1) ? T1 : T2;
    int r0 = blockIdx.y * 32, c0 = blockIdx.x * 32;
    tile[threadIdx.y][threadIdx.x] = W[(size_t)(r0 + threadIdx.y) * 768 + c0 + threadIdx.x];
    __syncthreads();
    T[(size_t)(c0 + threadIdx.y) * 768 + r0 + threadIdx.x] = f32_to_bf16(tile[threadIdx.x][threadIdx.y]);
}

// ---------------------------------------------------------------------------
// NT GEMM (m97 structure + XOR bank-swizzle): C = alpha * A[M,K] . B[N,K]^T
// LDS slot (row, cc) holds global chunk (row, cc ^ (row&7)); fragment reads
// use chunk^(row&7) -> quad's 16 rows spread over 8 bank groups (2-way, free)
// instead of all 16 on one group (the 1.9e7-conflict pattern).
// ---------------------------------------------------------------------------
template <typename CT>
__global__ __launch_bounds__(256) void gemm_nt(
    const unsigned short* __restrict__ A, const unsigned short* __restrict__ B,
    CT* __restrict__ C, int K, int lda, int ldb, int ldc,
    size_t sA, size_t sB, size_t sC, float alpha)
{
    A += (size_t)blockIdx.z * sA;
    B += (size_t)blockIdx.z * sB;
    C += (size_t)blockIdx.z * sC;
    const int m0 = blockIdx.y * 128;
    const int n0 = blockIdx.x * 128;
    const int t = threadIdx.x;
    const int lane = t & 63;
    const int w = t >> 6;
    const int wm = (w >> 1) * 64;   // wave row offset in tile
    const int wn = (w & 1) * 64;    // wave col offset in tile

    __shared__ unsigned short At[128 * 64];
    __shared__ unsigned short Bt[128 * 64];

    f32x4 acc[4][4];
#pragma unroll
    for (int i = 0; i < 4; ++i)
#pragma unroll
        for (int j = 0; j < 4; ++j) acc[i][j] = (f32x4){0.f, 0.f, 0.f, 0.f};

    const int r15 = lane & 15;
    const int qa = lane >> 4;       // fragment chunk index within 32-elem half

    for (int k0 = 0; k0 < K; k0 += 64) {
#pragma unroll
        for (int i = 0; i < 4; ++i) {
            const int c = i * 256 + t;            // LDS chunk id (8 bf16 each)
            const int row = c >> 3;
            const int cc = (c & 7) ^ (row & 7);   // swizzled global source chunk
            load16(A + (size_t)(m0 + row) * lda + k0 + cc * 8, &At[c * 8]);
            load16(B + (size_t)(n0 + row) * ldb + k0 + cc * 8, &Bt[c * 8]);
        }
        __syncthreads();

#pragma unroll
        for (int ks = 0; ks < 2; ++ks) {
            bf16x8 af[4], bf[4];
#pragma unroll
            for (int mi = 0; mi < 4; ++mi) {
                const int row = wm + mi * 16 + r15;
                af[mi] = *(const bf16x8*)&At[row * 64 + (((ks << 2) + qa) ^ (row & 7)) * 8];
            }
#pragma unroll
            for (int ni = 0; ni < 4; ++ni) {
                const int row = wn + ni * 16 + r15;
                bf[ni] = *(const bf16x8*)&Bt[row * 64 + (((ks << 2) + qa) ^ (row & 7)) * 8];
            }
#pragma unroll
            for (int mi = 0; mi < 4; ++mi)
#pragma unroll
                for (int ni = 0; ni < 4; ++ni)
                    acc[mi][ni] = __builtin_amdgcn_mfma_f32_16x16x32_bf16(
                        af[mi], bf[ni], acc[mi][ni], 0, 0, 0);
        }
        __syncthreads();
    }

    // epilogue: C/D layout col=lane&15, row=(lane>>4)*4+reg  [m89/m91 verified]
    const int cr = (lane >> 4) * 4;
#pragma unroll
    for (int mi = 0; mi < 4; ++mi) {
#pragma unroll
        for (int ni = 0; ni < 4; ++ni) {
            const int gm = m0 + wm + mi * 16 + cr;
            const int gn = n0 + wn + ni * 16 + r15;
#pragma unroll
            for (int r = 0; r < 4; ++r) {
                float v = alpha * acc[mi][ni][r];
                if constexpr (sizeof(CT) == 2)
                    C[(size_t)(gm + r) * ldc + gn] = (CT)f32_to_bf16(v);
                else
                    C[(size_t)(gm + r) * ldc + gn] = v;
            }
        }
    }
}

// ---------------------------------------------------------------------------
// Split-K O-GEMM, XCD-grouped swizzle + LDS bank swizzle. 768 blocks.
//   u = m*4 + split*2 + batch ; f = (u%8) + 8*(n + 6*(u/8))
// K-chunk = 2048. Part[z = split*2+batch][4096][768] fp32.
// ---------------------------------------------------------------------------
__global__ __launch_bounds__(256) void gemm_nt_splitk(
    const unsigned short* __restrict__ P, const unsigned short* __restrict__ Vt,
    float* __restrict__ Part)
{
    const int f = blockIdx.x;
    const int r8 = f & 7;
    const int tq = f >> 3;            // 0..95
    const int n  = tq % 6;
    const int v  = tq / 6;            // 0..15
    const int u  = v * 8 + r8;        // 0..127
    const int batch = u & 1;
    const int split = (u >> 1) & 1;
    const int m = u >> 2;             // 0..31

    const unsigned short* A = P + (size_t)batch * 16777216 + (size_t)split * 2048;
    const unsigned short* B = Vt + (size_t)batch * 4096 + (size_t)split * 2048;
    float* C = Part + (size_t)(split * 2 + batch) * 3145728;
    const int lda = 4096, ldb = 8192, ldc = 768;
    const int m0 = m * 128;
    const int n0 = n * 128;
    const int t = threadIdx.x;
    const int lane = t & 63;
    const int w = t >> 6;
    const int wm = (w >> 1) * 64;
    const int wn = (w & 1) * 64;

    __shared__ unsigned short At[128 * 64];
    __shared__ unsigned short Bt[128 * 64];

    f32x4 acc[4][4];
#pragma unroll
    for (int i = 0; i < 4; ++i)
#pragma unroll
        for (int j = 0; j < 4; ++j) acc[i][j] = (f32x4){0.f, 0.f, 0.f, 0.f};

    const int r15 = lane & 15;
    const int qa = lane >> 4;

    for (int k0 = 0; k0 < 2048; k0 += 64) {
#pragma unroll
        for (int i = 0; i < 4; ++i) {
            const int c = i * 256 + t;
            const int row = c >> 3;
            const int cc = (c & 7) ^ (row & 7);
            load16(A + (size_t)(m0 + row) * lda + k0 + cc * 8, &At[c * 8]);
            load16(B + (size_t)(n0 + row) * ldb + k0 + cc * 8, &Bt[c * 8]);
        }
        __syncthreads();

#pragma unroll
        for (int ks = 0; ks < 2; ++ks) {
            bf16x8 af[4], bf[4];
#pragma unroll
            for (int mi = 0; mi < 4; ++mi) {
                const int row = wm + mi * 16 + r15;
                af[mi] = *(const bf16x8*)&At[row * 64 + (((ks << 2) + qa) ^ (row & 7)) * 8];
            }
#pragma unroll
            for (int ni = 0; ni < 4; ++ni) {
                const int row = wn + ni * 16 + r15;
                bf[ni] = *(const bf16x8*)&Bt[row * 64 + (((ks << 2) + qa) ^ (row & 7)) * 8];
            }
#pragma unroll
            for (int mi = 0; mi < 4; ++mi)
#pragma unroll
                for (int ni = 0; ni < 4; ++ni)
                    acc[mi][ni] = __builtin_amdgcn_mfma_f32_16x16x32_bf16(
                        af[mi], bf[ni], acc[mi][ni], 0, 0, 0);
        }
        __syncthreads();
    }

    const int cr = (lane >> 4) * 4;
#pragma unroll
    for (int mi = 0; mi < 4; ++mi) {
#pragma unroll
        for (int ni = 0; ni < 4; ++ni) {
            const int gm = m0 + wm + mi * 16 + cr;
            const int gn = n0 + wn + ni * 16 + r15;
#pragma unroll
            for (int r = 0; r < 4; ++r)
                C[(size_t)(gm + r) * ldc + gn] = acc[mi][ni][r];
        }
    }
}

// ---------------------------------------------------------------------------
// Reduce 2 split-K partials: out4[i] = p4[i] + p4[i + 1572864]
// ---------------------------------------------------------------------------
__global__ __launch_bounds__(256) void reduce2(
    const float* __restrict__ Part, float* __restrict__ out)
{
    const size_t i = (size_t)blockIdx.x * 256 + threadIdx.x;  // float4 index
    const f32x4* p = (const f32x4*)Part;
    ((f32x4*)out)[i] = p[i] + p[i + 1572864];
}

// ---------------------------------------------------------------------------
// Row softmax: S (fp32, 4096 cols) -> P (bf16). One block per row.
// ---------------------------------------------------------------------------
__global__ __launch_bounds__(256) void softmax_rows(
    const float* __restrict__ S, unsigned short* __restrict__ P)
{
    const size_t row = blockIdx.x;
    const float* s = S + row * 4096;
    unsigned short* p = P + row * 4096;
    const int t = threadIdx.x;
    const int wv = t >> 6, ln = t & 63;

    float4 v[4];
    float lmax = -1e30f;
#pragma unroll
    for (int i = 0; i < 4; ++i) {
        v[i] = ((const float4*)s)[t + i * 256];
        lmax = fmaxf(lmax, fmaxf(fmaxf(v[i].x, v[i].y), fmaxf(v[i].z, v[i].w)));
    }
#pragma unroll
    for (int off = 32; off > 0; off >>= 1) lmax = fmaxf(lmax, __shfl_down(lmax, off, 64));
    __shared__ float redm[4], reds[4];
    if (ln == 0) redm[wv] = lmax;
    __syncthreads();
    const float rmax = fmaxf(fmaxf(redm[0], redm[1]), fmaxf(redm[2], redm[3]));

    float lsum = 0.f;
#pragma unroll
    for (int i = 0; i < 4; ++i) {
        v[i].x = __expf(v[i].x - rmax);
        v[i].y = __expf(v[i].y - rmax);
        v[i].z = __expf(v[i].z - rmax);
        v[i].w = __expf(v[i].w - rmax);
        lsum += v[i].x + v[i].y + v[i].z + v[i].w;
    }
#pragma unroll
    for (int off = 32; off > 0; off >>= 1) lsum += __shfl_down(lsum, off, 64);
    if (ln == 0) reds[wv] = lsum;
    __syncthreads();
    const float inv = 1.f / (reds[0] + reds[1] + reds[2] + reds[3]);

#pragma unroll
    for (int i = 0; i < 4; ++i) {
        ushort4 o;
        o.x = f32_to_bf16(v[i].x * inv);
        o.y = f32_to_bf16(v[i].y * inv);
        o.z = f32_to_bf16(v[i].z * inv);
        o.w = f32_to_bf16(v[i].w * inv);
        ((ushort4*)p)[t + i * 256] = o;
    }
}

// ---------------------------------------------------------------------------
extern "C" void kernel_launch(void* const* d_in, const int* in_sizes, int n_in,
                              void* d_out, int out_size, void* d_ws, size_t ws_size,
                              hipStream_t stream) {
    const float* x  = (const float*)d_in[0];   // [2,4096,768]
    const float* Wq = (const float*)d_in[1];   // [768,768]
    const float* Wk = (const float*)d_in[2];
    const float* Wv = (const float*)d_in[3];
    float* out = (float*)d_out;                // [2,4096,768] fp32

    char* base = (char*)d_ws;
    size_t off = 0;
    auto alloc = [&](size_t b) { char* p = base + off; off += (b + 255) & ~(size_t)255; return p; };

    unsigned short* Xbf = (unsigned short*)alloc(8192ull * 768 * 2);   // x as bf16
    unsigned short* WqT = (unsigned short*)alloc(768ull * 768 * 2);    // Wq^T bf16
    unsigned short* WkT = (unsigned short*)alloc(768ull * 768 * 2);    // contiguous after WqT
    unsigned short* WvT = (unsigned short*)alloc(768ull * 768 * 2);
    unsigned short* Qb  = (unsigned short*)alloc(8192ull * 768 * 2);   // Q bf16 [8192,768]
    unsigned short* Kb  = (unsigned short*)alloc(8192ull * 768 * 2);   // contiguous after Qb
    unsigned short* Vt  = (unsigned short*)alloc(768ull * 8192 * 2);   // V^T bf16 [768,8192]
    float*          S   = (float*)alloc(2ull * 4096 * 4096 * 4);       // scores fp32; reused for O partials
    unsigned short* P   = (unsigned short*)alloc(2ull * 4096 * 4096 * 2); // softmax bf16
    (void)ws_size; (void)in_sizes; (void)n_in; (void)out_size;

    // 1) x -> bf16
    convert_f32_bf16<<<dim3(6144), dim3(256), 0, stream>>>(x, Xbf, 8192 * 768 / 4);
    // 2) W -> W^T bf16 (all three)
    transpose_w<<<dim3(24, 24, 3), dim3(32, 32), 0, stream>>>(Wq, Wk, Wv, WqT, WkT, WvT);
    // 3) Q,K = Xbf . W^T^T  (NT; z=0 -> Q, z=1 -> K via buffer strides)
    gemm_nt<unsigned short><<<dim3(6, 64, 2), dim3(256), 0, stream>>>(
        Xbf, WqT, Qb, 768, 768, 768, 768,
        /*sA*/ 0, /*sB*/ 589824, /*sC*/ 6291456, 1.0f);
    // 4) V^T = WvT . Xbf^T  (NT) -> [768, 8192]
    gemm_nt<unsigned short><<<dim3(64, 6, 1), dim3(256), 0, stream>>>(
        WvT, Xbf, Vt, 768, 768, 768, 8192, 0, 0, 0, 1.0f);
    // 5) S = (Q . K^T) / sqrt(768), fp32, per batch
    gemm_nt<float><<<dim3(32, 32, 2), dim3(256), 0, stream>>>(
        Qb, Kb, S, 768, 768, 768, 4096,
        /*sA*/ 3145728ull, /*sB*/ 3145728ull, /*sC*/ 16777216ull, 0.03608439182435161f);
    // 6) row softmax -> P bf16
    softmax_rows<<<dim3(8192), dim3(256), 0, stream>>>(S, P);
    // 7) O = P . V via 2-way split-K, XCD-grouped swizzle, 768 blocks all-resident
    gemm_nt_splitk<<<dim3(768), dim3(256), 0, stream>>>(P, Vt, (float*)S);
    reduce2<<<dim3(6144), dim3(256), 0, stream>>>((const float*)S, out);
}